// Round 8
// baseline (868.528 us; speedup 1.0000x reference)
//
#include <hip/hip_runtime.h>

// ---------- bf16 helpers (bit-level, RNE) ----------
__device__ __forceinline__ float bf2f(unsigned short u) {
    union { unsigned int i; float f; } v;
    v.i = ((unsigned int)u) << 16;
    return v.f;
}
__device__ __forceinline__ unsigned short f2bf(float f) {
    union { float f; unsigned int u; } v;
    v.f = f;
    unsigned int u = v.u;
    u += 0x7FFFu + ((u >> 16) & 1u);   // round-to-nearest-even
    return (unsigned short)(u >> 16);
}
__device__ __forceinline__ float loadElem(const void* p, size_t i, int isb) {
    return isb ? bf2f(((const unsigned short*)p)[i]) : ((const float*)p)[i];
}
__device__ __forceinline__ void fma4(float4& a, float s, const float4& w) {
    a.x += s * w.x; a.y += s * w.y; a.z += s * w.z; a.w += s * w.w;
}
__device__ __forceinline__ void unpack8(uint4 u, float* v) {
    v[0] = bf2f((unsigned short)(u.x & 0xFFFF)); v[1] = bf2f((unsigned short)(u.x >> 16));
    v[2] = bf2f((unsigned short)(u.y & 0xFFFF)); v[3] = bf2f((unsigned short)(u.y >> 16));
    v[4] = bf2f((unsigned short)(u.z & 0xFFFF)); v[5] = bf2f((unsigned short)(u.z >> 16));
    v[6] = bf2f((unsigned short)(u.w & 0xFFFF)); v[7] = bf2f((unsigned short)(u.w >> 16));
}

#define CHUNK 8192            // edges per partition block
#define BSHIFT 6              // 64 nodes per bucket (LDS-resident accumulator)
#define BNODES 64
#define MAXBUK 1600           // supports N <= 102400

// ---------- runtime dtype detection (proven r3-r7) ----------
__global__ void k_detect(const int* __restrict__ ei, int newords,
                         const unsigned int* __restrict__ xw, int nxw,
                         int* __restrict__ flags) {
    __shared__ int aOr;
    __shared__ int plaus;
    if (threadIdx.x == 0) { aOr = 0; plaus = 0; }
    __syncthreads();
    int v = 0;
    for (int i = 1 + 2 * (int)threadIdx.x; i < newords; i += 512) v |= ei[i];
    int pl = 0;
    for (int i = threadIdx.x; i < nxw; i += 256) {
        unsigned short lo = (unsigned short)(xw[i] & 0xFFFFu);
        float a = fabsf(bf2f(lo));
        if (a > 1e-5f && a < 100.0f) pl++;
    }
    atomicOr(&aOr, v);
    atomicAdd(&plaus, pl);
    __syncthreads();
    if (threadIdx.x == 0) {
        flags[0] = (aOr == 0) ? 1 : 0;
        flags[1] = (2 * plaus >= nxw) ? 1 : 0;
    }
}

// ---------- bucket counting sort (proven r6/r7, rebased to 64-node buckets) ----------
__global__ __launch_bounds__(256) void k_bcount(
        const int* __restrict__ ei, const int* __restrict__ flags,
        int* __restrict__ blockHist, int E, int NBUK, int nblk) {
    __shared__ int hist[MAXBUK];
    int t = threadIdx.x;
    for (int i = t; i < NBUK; i += 256) hist[i] = 0;
    __syncthreads();
    int q = flags[0];
    int e0 = blockIdx.x * CHUNK, e1 = min(E, e0 + CHUNK);
    for (int e = e0 + t; e < e1; e += 256) {
        int dst = ei[((size_t)(E + e)) << q];
        atomicAdd(&hist[dst >> BSHIFT], 1);
    }
    __syncthreads();
    for (int i = t; i < NBUK; i += 256)
        blockHist[(size_t)i * nblk + blockIdx.x] = hist[i];
}

// one block per bucket: exclusive scan of its row in place + bucket total
__global__ __launch_bounds__(256) void k_rowscan(
        int* __restrict__ blockHist, int* __restrict__ bukTot, int nblk) {
    __shared__ int sh[256];
    int t = threadIdx.x;
    int* row = blockHist + (size_t)blockIdx.x * nblk;
    int carry = 0;
    for (int base = 0; base < nblk; base += 256) {
        int i = base + t;
        int v = (i < nblk) ? row[i] : 0;
        sh[t] = v;
        __syncthreads();
        for (int off = 1; off < 256; off <<= 1) {
            int u = (t >= off) ? sh[t - off] : 0;
            __syncthreads();
            sh[t] += u;
            __syncthreads();
        }
        if (i < nblk) row[i] = carry + sh[t] - v;
        int tot = sh[255];
        __syncthreads();
        carry += tot;
    }
    if (t == 0) bukTot[blockIdx.x] = carry;
}

// single-block tiled exclusive scan of bucket totals -> bukOff
__global__ __launch_bounds__(1024) void k_toto(
        const int* __restrict__ bukTot, int* __restrict__ bukOff, int NBUK, int E) {
    __shared__ int sh[1024];
    int t = threadIdx.x;
    int carry = 0;
    for (int base = 0; base < NBUK; base += 1024) {
        int i = base + t;
        int v = (i < NBUK) ? bukTot[i] : 0;
        sh[t] = v;
        __syncthreads();
        for (int off = 1; off < 1024; off <<= 1) {
            int u = (t >= off) ? sh[t - off] : 0;
            __syncthreads();
            sh[t] += u;
            __syncthreads();
        }
        if (i < NBUK) bukOff[i] = carry + sh[t] - v;
        int tot = sh[1023];
        __syncthreads();
        carry += tot;
    }
    if (t == 0) bukOff[NBUK] = E;
}

// partition edges into bucket-grouped packed records (src<<6 | dstLocal)
__global__ __launch_bounds__(256) void k_part(
        const int* __restrict__ ei, const int* __restrict__ flags,
        const int* __restrict__ blockHist, const int* __restrict__ bukOff,
        unsigned int* __restrict__ recs, int E, int NBUK, int nblk) {
    __shared__ int cur[MAXBUK];
    int t = threadIdx.x;
    for (int i = t; i < NBUK; i += 256)
        cur[i] = blockHist[(size_t)i * nblk + blockIdx.x] + bukOff[i];
    __syncthreads();
    int q = flags[0];
    int e0 = blockIdx.x * CHUNK, e1 = min(E, e0 + CHUNK);
    for (int e = e0 + t; e < e1; e += 256) {
        int dst = ei[((size_t)(E + e)) << q];
        int src = ei[((size_t)e) << q];
        int pos = atomicAdd(&cur[dst >> BSHIFT], 1);
        recs[pos] = ((unsigned int)src << BSHIFT) | (unsigned int)(dst & (BNODES - 1));
    }
}

// ---------- register-tiled dense GEMM (r5, staging vectorized) ----------
template<int CHOUT, int NPB>
__global__ __launch_bounds__(256) void k_gemm(
        const void* __restrict__ A, int aIsB,
        const void* __restrict__ W,
        unsigned short* __restrict__ D, int N, const int* __restrict__ flags) {
    constexpr int S = NPB + 2;
    __shared__ float As[64 * S];
    __shared__ float Ws[64 * CHOUT];

    int isb = flags[1];
    int ab = (aIsB >= 0) ? aIsB : isb;
    int t = threadIdx.x;

    if (isb) {
        for (int i = t; i < (64 * CHOUT) / 8; i += 256) {
            uint4 u = *(const uint4*)((const unsigned short*)W + (size_t)i * 8);
            float v[8]; unpack8(u, v);
#pragma unroll
            for (int j = 0; j < 8; ++j) Ws[i * 8 + j] = v[j];
        }
    } else {
        for (int i = t; i < 64 * CHOUT; i += 256) Ws[i] = ((const float*)W)[i];
    }

    int nodeBase = blockIdx.x * NPB;
    if (ab) {
        for (int i = t; i < NPB * 8; i += 256) {
            int node = i >> 3, k0 = (i & 7) << 3;
            int gn = nodeBase + node;
            float v[8];
            if (gn < N) {
                uint4 u = *(const uint4*)((const unsigned short*)A + (size_t)gn * 64 + k0);
                unpack8(u, v);
            } else {
#pragma unroll
                for (int j = 0; j < 8; ++j) v[j] = 0.f;
            }
#pragma unroll
            for (int j = 0; j < 8; ++j) As[(k0 + j) * S + node] = v[j];
        }
    } else {
        for (int i = t; i < NPB * 64; i += 256) {
            int node = i >> 6, k = i & 63;
            int gn = nodeBase + node;
            As[k * S + node] = (gn < N) ? ((const float*)A)[(size_t)gn * 64 + k] : 0.f;
        }
    }
    __syncthreads();

    constexpr int CQ = CHOUT / 4;
    int cq = t % CQ, nq = t / CQ;
    float4 acc[4];
    acc[0] = acc[1] = acc[2] = acc[3] = make_float4(0.f, 0.f, 0.f, 0.f);

#pragma unroll 8
    for (int k = 0; k < 64; ++k) {
        const float* ar = &As[k * S + 4 * nq];
        float2 a01 = *(const float2*)ar;
        float2 a23 = *(const float2*)(ar + 2);
        float4 w = *(const float4*)&Ws[k * CHOUT + 4 * cq];
        fma4(acc[0], a01.x, w);
        fma4(acc[1], a01.y, w);
        fma4(acc[2], a23.x, w);
        fma4(acc[3], a23.y, w);
    }

#pragma unroll
    for (int i = 0; i < 4; ++i) {
        int node = nodeBase + 4 * nq + i;
        if (node >= N) continue;
        float4 r = acc[i];
        ushort4 o = { f2bf(r.x), f2bf(r.y), f2bf(r.z), f2bf(r.w) };
        *(ushort4*)(D + (size_t)node * CHOUT + 4 * cq) = o;
    }
}

// ---------- fused bucket-local aggregation + GEMM ----------
// One workgroup per 64-node bucket:
//   phase 1: stream recs, LDS-atomicAdd feat rows into am[64][CHOUT] (f32), count deg
//   phase 2: out = act( own@W + am/deg + bias )
template<int CHOUT, bool RELU, bool FINAL>
__global__ __launch_bounds__(256) void k_fused(
        const unsigned short* __restrict__ feat,   // [N,CHOUT] bf16 (y1/y2)
        const void* __restrict__ own,              // [N,64]
        int ownIsB,
        const unsigned int* __restrict__ recs,
        const int* __restrict__ bukOff,
        const void* __restrict__ W,                // [64,CHOUT]
        const void* __restrict__ bias,             // [CHOUT]
        void* __restrict__ outp,                   // [N,CHOUT]
        int N, const int* __restrict__ flags) {
    constexpr int SA = CHOUT + 1;     // am stride (odd -> bank-spread LDS atomics)
    constexpr int SX = BNODES + 2;
    __shared__ float am[BNODES * SA];
    __shared__ float As[64 * SX];
    __shared__ float Ws[64 * CHOUT];
    __shared__ float Bs[CHOUT];
    __shared__ int   deg[BNODES];
    __shared__ float invdeg[BNODES];

    int t = threadIdx.x;
    int isb = flags[1];
    int ob = (ownIsB >= 0) ? ownIsB : isb;
    int node0 = blockIdx.x << BSHIFT;

    for (int i = t; i < BNODES * SA; i += 256) am[i] = 0.f;
    if (t < BNODES) deg[t] = 0;
    if (isb) {
        for (int i = t; i < (64 * CHOUT) / 8; i += 256) {
            uint4 u = *(const uint4*)((const unsigned short*)W + (size_t)i * 8);
            float v[8]; unpack8(u, v);
#pragma unroll
            for (int j = 0; j < 8; ++j) Ws[i * 8 + j] = v[j];
        }
    } else {
        for (int i = t; i < 64 * CHOUT; i += 256) Ws[i] = ((const float*)W)[i];
    }
    if (t < CHOUT) Bs[t] = loadElem(bias, t, isb);
    if (ob) {
        for (int i = t; i < BNODES * 8; i += 256) {
            int node = i >> 3, k0 = (i & 7) << 3;
            int gn = node0 + node;
            float v[8];
            if (gn < N) {
                uint4 u = *(const uint4*)((const unsigned short*)own + (size_t)gn * 64 + k0);
                unpack8(u, v);
            } else {
#pragma unroll
                for (int j = 0; j < 8; ++j) v[j] = 0.f;
            }
#pragma unroll
            for (int j = 0; j < 8; ++j) As[(k0 + j) * SX + node] = v[j];
        }
    } else {
        for (int i = t; i < BNODES * 64; i += 256) {
            int node = i >> 6, k = i & 63;
            int gn = node0 + node;
            As[k * SX + node] = (gn < N) ? ((const float*)own)[(size_t)gn * 64 + k] : 0.f;
        }
    }
    __syncthreads();

    // ---- phase 1: edge aggregation into LDS ----
    {
        int r0 = bukOff[blockIdx.x], r1 = bukOff[blockIdx.x + 1];
        constexpr int SLOTS = 256 / CHOUT;           // 4 (CH=64) or 8 (CH=32)
        int slot = t / CHOUT, ch = t % CHOUT;
        for (int i = r0 + slot; i < r1; i += SLOTS * 4) {
            int i1 = i + SLOTS, i2 = i + 2 * SLOTS, i3 = i + 3 * SLOTS;
            unsigned int rA = recs[i];
            unsigned int rB = (i1 < r1) ? recs[i1] : rA;
            unsigned int rC = (i2 < r1) ? recs[i2] : rA;
            unsigned int rD = (i3 < r1) ? recs[i3] : rA;
            float vA = bf2f(feat[(size_t)(rA >> BSHIFT) * CHOUT + ch]);
            float vB = bf2f(feat[(size_t)(rB >> BSHIFT) * CHOUT + ch]);
            float vC = bf2f(feat[(size_t)(rC >> BSHIFT) * CHOUT + ch]);
            float vD = bf2f(feat[(size_t)(rD >> BSHIFT) * CHOUT + ch]);
            atomicAdd(&am[(rA & (BNODES - 1)) * SA + ch], vA);
            if (i1 < r1) atomicAdd(&am[(rB & (BNODES - 1)) * SA + ch], vB);
            if (i2 < r1) atomicAdd(&am[(rC & (BNODES - 1)) * SA + ch], vC);
            if (i3 < r1) atomicAdd(&am[(rD & (BNODES - 1)) * SA + ch], vD);
            if (ch == 0) {
                atomicAdd(&deg[rA & (BNODES - 1)], 1);
                if (i1 < r1) atomicAdd(&deg[rB & (BNODES - 1)], 1);
                if (i2 < r1) atomicAdd(&deg[rC & (BNODES - 1)], 1);
                if (i3 < r1) atomicAdd(&deg[rD & (BNODES - 1)], 1);
            }
        }
    }
    __syncthreads();
    if (t < BNODES) invdeg[t] = 1.0f / (float)max(deg[t], 1);
    __syncthreads();

    // ---- phase 2: GEMM + epilogue ----
    constexpr int CQ = CHOUT / 4;
    constexpr int NPT = CHOUT / 16;                  // 4 (CH=64) or 2 (CH=32)
    int cq = t % CQ, nq = t / CQ;
    float4 acc[NPT];
#pragma unroll
    for (int j = 0; j < NPT; ++j) acc[j] = make_float4(0.f, 0.f, 0.f, 0.f);

#pragma unroll 8
    for (int k = 0; k < 64; ++k) {
        const float* ar = &As[k * SX + NPT * nq];
        float4 w = *(const float4*)&Ws[k * CHOUT + 4 * cq];
#pragma unroll
        for (int j = 0; j < NPT; ++j) fma4(acc[j], ar[j], w);
    }

    float4 bv = *(const float4*)&Bs[4 * cq];
#pragma unroll
    for (int j = 0; j < NPT; ++j) {
        int nl = NPT * nq + j;
        int node = node0 + nl;
        if (node >= N) continue;
        float id = invdeg[nl];
        float4 r = acc[j];
        const float* ap = &am[nl * SA + 4 * cq];
        r.x += ap[0] * id + bv.x;
        r.y += ap[1] * id + bv.y;
        r.z += ap[2] * id + bv.z;
        r.w += ap[3] * id + bv.w;
        if (RELU) {
            r.x = fmaxf(r.x, 0.f); r.y = fmaxf(r.y, 0.f);
            r.z = fmaxf(r.z, 0.f); r.w = fmaxf(r.w, 0.f);
        }
        if (FINAL && !isb) {
            *(float4*)((float*)outp + (size_t)node * CHOUT + 4 * cq) = r;
        } else {
            ushort4 o = { f2bf(r.x), f2bf(r.y), f2bf(r.z), f2bf(r.w) };
            *(ushort4*)((unsigned short*)outp + (size_t)node * CHOUT + 4 * cq) = o;
        }
    }
}

extern "C" void kernel_launch(void* const* d_in, const int* in_sizes, int n_in,
                              void* d_out, int out_size, void* d_ws, size_t ws_size,
                              hipStream_t stream) {
    const void* x   = d_in[0];
    const int*  ei  = (const int*)d_in[1];
    const void* W1l = d_in[2];
    const void* W1r = d_in[3];
    const void* b1  = d_in[4];
    const void* W2l = d_in[5];
    const void* W2r = d_in[6];
    const void* b2  = d_in[7];

    const int N = in_sizes[0] / 64;
    const int E = in_sizes[1] / 2;
    const int NBUK = (N + BNODES - 1) >> BSHIFT;      // 1563 @ N=100k (<= MAXBUK)
    const int nblk = (E + CHUNK - 1) / CHUNK;         // 147 @ E=1.2M

    // ws: flags | bukTot | bukOff | recs[E] | bufY (blockHist overlay; y1 then y2) | bufH
    char* base = (char*)d_ws;
    size_t off = 0;
    auto alloc = [&](size_t bytes) { size_t o = off; off = (off + bytes + 255) & ~(size_t)255; return o; };
    int* flags   = (int*)(base + alloc(256));
    int* bukTot  = (int*)(base + alloc((size_t)NBUK * 4));
    int* bukOff  = (int*)(base + alloc((size_t)(NBUK + 1) * 4));
    unsigned int* recs = (unsigned int*)(base + alloc((size_t)E * 4));
    unsigned short* bufY = (unsigned short*)(base + alloc((size_t)N * 64 * 2));
    unsigned short* bufH = (unsigned short*)(base + alloc((size_t)N * 64 * 2));
    (void)ws_size;

    int* blockHist = (int*)bufY;    // [NBUK][nblk], dead before gemm1 writes y1

    const int B = 256;
    int nd = 2 * E; if (nd > 2048) nd = 2048;

    k_detect<<<1, 256, 0, stream>>>(ei, nd, (const unsigned int*)x, 512, flags);
    k_bcount<<<nblk, B, 0, stream>>>(ei, flags, blockHist, E, NBUK, nblk);
    k_rowscan<<<NBUK, B, 0, stream>>>(blockHist, bukTot, nblk);
    k_toto<<<1, 1024, 0, stream>>>(bukTot, bukOff, NBUK, E);
    k_part<<<nblk, B, 0, stream>>>(ei, flags, blockHist, bukOff, recs, E, NBUK, nblk);

    unsigned short* y1 = bufY;
    unsigned short* h  = bufH;
    unsigned short* y2 = bufY;      // overlays y1 (dead after fusedA)

    // y1 = x @ W1l
    k_gemm<64, 64><<<(N + 63) / 64, B, 0, stream>>>(x, -1, W1l, y1, N, flags);
    // h = relu( x @ W1r + mean_nbr(y1) + b1 )
    k_fused<64, true, false><<<NBUK, B, 0, stream>>>(y1, x, -1, recs, bukOff,
                                                     W1r, b1, h, N, flags);
    // y2 = h @ W2l
    k_gemm<32, 128><<<(N + 127) / 128, B, 0, stream>>>(h, 1, W2l, y2, N, flags);
    // out = h @ W2r + mean_nbr(y2) + b2
    k_fused<32, false, true><<<NBUK, B, 0, stream>>>(y2, h, 1, recs, bukOff,
                                                     W2r, b2, d_out, N, flags);
}

// Round 9
// 243.117 us; speedup vs baseline: 3.5725x; 3.5725x over previous
//
#include <hip/hip_runtime.h>

// ---------- bf16 helpers (bit-level, RNE) ----------
__device__ __forceinline__ float bf2f(unsigned short u) {
    union { unsigned int i; float f; } v;
    v.i = ((unsigned int)u) << 16;
    return v.f;
}
__device__ __forceinline__ unsigned short f2bf(float f) {
    union { float f; unsigned int u; } v;
    v.f = f;
    unsigned int u = v.u;
    u += 0x7FFFu + ((u >> 16) & 1u);   // round-to-nearest-even
    return (unsigned short)(u >> 16);
}
__device__ __forceinline__ float loadElem(const void* p, size_t i, int isb) {
    return isb ? bf2f(((const unsigned short*)p)[i]) : ((const float*)p)[i];
}
__device__ __forceinline__ void fma4(float4& a, float s, const float4& w) {
    a.x += s * w.x; a.y += s * w.y; a.z += s * w.z; a.w += s * w.w;
}
__device__ __forceinline__ void unpack8(uint4 u, float* v) {
    v[0] = bf2f((unsigned short)(u.x & 0xFFFF)); v[1] = bf2f((unsigned short)(u.x >> 16));
    v[2] = bf2f((unsigned short)(u.y & 0xFFFF)); v[3] = bf2f((unsigned short)(u.y >> 16));
    v[4] = bf2f((unsigned short)(u.z & 0xFFFF)); v[5] = bf2f((unsigned short)(u.z >> 16));
    v[6] = bf2f((unsigned short)(u.w & 0xFFFF)); v[7] = bf2f((unsigned short)(u.w >> 16));
}

#define CHUNK 4096            // edges per partition block (r7 proven)
#define BSHIFT 8              // 256 nodes per sort bucket (r7 proven)

// ---------- runtime dtype detection (proven r3-r8) ----------
__global__ void k_detect(const int* __restrict__ ei, int newords,
                         const unsigned int* __restrict__ xw, int nxw,
                         int* __restrict__ flags) {
    __shared__ int aOr;
    __shared__ int plaus;
    if (threadIdx.x == 0) { aOr = 0; plaus = 0; }
    __syncthreads();
    int v = 0;
    for (int i = 1 + 2 * (int)threadIdx.x; i < newords; i += 512) v |= ei[i];
    int pl = 0;
    for (int i = threadIdx.x; i < nxw; i += 256) {
        unsigned short lo = (unsigned short)(xw[i] & 0xFFFFu);
        float a = fabsf(bf2f(lo));
        if (a > 1e-5f && a < 100.0f) pl++;
    }
    atomicOr(&aOr, v);
    atomicAdd(&plaus, pl);
    __syncthreads();
    if (threadIdx.x == 0) {
        flags[0] = (aOr == 0) ? 1 : 0;
        flags[1] = (2 * plaus >= nxw) ? 1 : 0;
    }
}

// ---------- cast x -> bf16 (copy-through if already bf16) ----------
__global__ void k_cast(const void* __restrict__ x, unsigned short* __restrict__ xb,
                       int n8, const int* __restrict__ flags) {
    int i = blockIdx.x * blockDim.x + threadIdx.x;
    if (i >= n8) return;
    if (flags[1]) {
        ((uint4*)xb)[i] = ((const uint4*)x)[i];
    } else {
        const float4* xf = (const float4*)x;
        float4 a = xf[2 * i], b = xf[2 * i + 1];
        ushort4 lo = { f2bf(a.x), f2bf(a.y), f2bf(a.z), f2bf(a.w) };
        ushort4 hi = { f2bf(b.x), f2bf(b.y), f2bf(b.z), f2bf(b.w) };
        ((ushort4*)xb)[2 * i] = lo;
        ((ushort4*)xb)[2 * i + 1] = hi;
    }
}

// ---------- CSR build: counting sort with parallel scans (r7 verbatim) ----------
__global__ __launch_bounds__(256) void k_bcount(
        const int* __restrict__ ei, const int* __restrict__ flags,
        int* __restrict__ blockHist, int E, int NBUK, int nblk) {
    __shared__ int hist[512];
    int t = threadIdx.x;
    for (int i = t; i < NBUK; i += 256) hist[i] = 0;
    __syncthreads();
    int q = flags[0];
    int e0 = blockIdx.x * CHUNK, e1 = min(E, e0 + CHUNK);
    for (int e = e0 + t; e < e1; e += 256) {
        int dst = ei[((size_t)(E + e)) << q];
        atomicAdd(&hist[dst >> BSHIFT], 1);
    }
    __syncthreads();
    for (int i = t; i < NBUK; i += 256)
        blockHist[(size_t)i * nblk + blockIdx.x] = hist[i];
}

__global__ __launch_bounds__(256) void k_rowscan(
        int* __restrict__ blockHist, int* __restrict__ bukTot, int nblk) {
    __shared__ int sh[256];
    int t = threadIdx.x;
    int* row = blockHist + (size_t)blockIdx.x * nblk;
    int carry = 0;
    for (int base = 0; base < nblk; base += 256) {
        int i = base + t;
        int v = (i < nblk) ? row[i] : 0;
        sh[t] = v;
        __syncthreads();
        for (int off = 1; off < 256; off <<= 1) {
            int u = (t >= off) ? sh[t - off] : 0;
            __syncthreads();
            sh[t] += u;
            __syncthreads();
        }
        if (i < nblk) row[i] = carry + sh[t] - v;
        int tot = sh[255];
        __syncthreads();
        carry += tot;
    }
    if (t == 0) bukTot[blockIdx.x] = carry;
}

__global__ __launch_bounds__(512) void k_toto(
        const int* __restrict__ bukTot, int* __restrict__ bukOff,
        int* __restrict__ rowptr, int NBUK, int E, int N) {
    __shared__ int sh[512];
    int t = threadIdx.x;
    int v = (t < NBUK) ? bukTot[t] : 0;
    sh[t] = v;
    __syncthreads();
    for (int off = 1; off < 512; off <<= 1) {
        int u = (t >= off) ? sh[t - off] : 0;
        __syncthreads();
        sh[t] += u;
        __syncthreads();
    }
    if (t < NBUK) bukOff[t] = sh[t] - v;
    if (t == 0) { bukOff[NBUK] = E; rowptr[N] = E; }
}

__global__ __launch_bounds__(256) void k_part(
        const int* __restrict__ ei, const int* __restrict__ flags,
        const int* __restrict__ blockHist, const int* __restrict__ bukOff,
        unsigned int* __restrict__ recs, int E, int NBUK, int nblk) {
    __shared__ int cur[512];
    int t = threadIdx.x;
    for (int i = t; i < NBUK; i += 256)
        cur[i] = blockHist[(size_t)i * nblk + blockIdx.x] + bukOff[i];
    __syncthreads();
    int q = flags[0];
    int e0 = blockIdx.x * CHUNK, e1 = min(E, e0 + CHUNK);
    for (int e = e0 + t; e < e1; e += 256) {
        int dst = ei[((size_t)(E + e)) << q];
        int src = ei[((size_t)e) << q];
        int pos = atomicAdd(&cur[dst >> BSHIFT], 1);
        recs[pos] = ((unsigned int)src << BSHIFT) | (unsigned int)(dst & ((1 << BSHIFT) - 1));
    }
}

__global__ __launch_bounds__(256) void k_csr(
        const unsigned int* __restrict__ recs, const int* __restrict__ bukOff,
        int* __restrict__ rowptr, int* __restrict__ esorted, int N) {
    __shared__ int degLoc[256];
    __shared__ int offLoc[256];
    __shared__ int wcur[256];
    int t = threadIdx.x;
    int node0 = blockIdx.x << BSHIFT;
    int r0 = bukOff[blockIdx.x], r1 = bukOff[blockIdx.x + 1];
    degLoc[t] = 0;
    __syncthreads();
    for (int i = r0 + t; i < r1; i += 256)
        atomicAdd(&degLoc[recs[i] & 255], 1);
    __syncthreads();
    int v = degLoc[t];
    offLoc[t] = v;
    __syncthreads();
    for (int off = 1; off < 256; off <<= 1) {
        int u = (t >= off) ? offLoc[t - off] : 0;
        __syncthreads();
        offLoc[t] += u;
        __syncthreads();
    }
    int excl = offLoc[t] - v;
    int node = node0 + t;
    if (node < N) rowptr[node] = r0 + excl;
    wcur[t] = r0 + excl;
    __syncthreads();
    for (int i = r0 + t; i < r1; i += 256) {
        unsigned int rec = recs[i];
        int pos = atomicAdd(&wcur[rec & 255], 1);
        esorted[pos] = (int)(rec >> BSHIFT);
    }
}

// ---------- fused layer: CSR register-gather (no atomics) + double GEMM ----------
// One block = 64 nodes. Phase 1: 16-lane groups gather mean_nbr(feat) -> amBuf[nl][k]
// (r5's proven 4-row-ILP shfl pattern, exclusive LDS ownership). Phase 2:
// acc = am @ Wl. Restage (am dead -> own rows; Wl -> Wr). Phase 3:
// acc += own @ Wr. Epilogue: +bias, optional relu, store.
template<int CHOUT, bool RELU, bool FINAL>
__global__ __launch_bounds__(256) void k_fused(
        const unsigned short* __restrict__ feat,   // [N,64] bf16: xb (L1) or h (L2)
        const int* __restrict__ rowptr,
        const int* __restrict__ esorted,
        const void* __restrict__ Wl,               // [64,CHOUT]
        const void* __restrict__ Wr,               // [64,CHOUT]
        const void* __restrict__ bias,             // [CHOUT]
        void* __restrict__ outp,                   // [N,CHOUT]
        int N, const int* __restrict__ flags) {
    constexpr int SA = 68;                         // 16B-aligned float4, bank-spread
    __shared__ float amBuf[64 * SA];
    __shared__ float wS[64 * CHOUT];
    __shared__ float Bs[CHOUT];

    int t = threadIdx.x;
    int isb = flags[1];
    int node0 = blockIdx.x << 6;

    // stage Wl
    if (isb) {
        for (int i = t; i < (64 * CHOUT) / 8; i += 256) {
            uint4 u = *(const uint4*)((const unsigned short*)Wl + (size_t)i * 8);
            float v[8]; unpack8(u, v);
#pragma unroll
            for (int j = 0; j < 8; ++j) wS[i * 8 + j] = v[j];
        }
    } else {
        for (int i = t; i < 64 * CHOUT; i += 256) wS[i] = ((const float*)Wl)[i];
    }
    if (t < CHOUT) Bs[t] = loadElem(bias, t, isb);

    // ---- phase 1: gather mean of neighbor rows -> amBuf[nl][k] ----
    {
        int g = t >> 4, l = t & 15;
        int gb = (t & 63) & ~15;                   // group base lane within wave
#pragma unroll
        for (int jj = 0; jj < 4; ++jj) {
            int nl = g + 16 * jj;
            int node = node0 + nl;
            float ax = 0.f, ay = 0.f, az = 0.f, aw = 0.f;
            float inv = 0.f;
            if (node < N) {
                int beg = rowptr[node], end = rowptr[node + 1];
                int d = end - beg;
                if (d > 0) {
                    inv = 1.0f / (float)d;
                    for (int bs = beg; bs < end; bs += 16) {
                        int cnt = min(end - bs, 16);
                        int idx = esorted[min(bs + l, end - 1)];
                        int dd = 0;
                        for (; dd + 4 <= cnt; dd += 4) {
                            int s0 = __shfl(idx, gb + dd + 0, 64);
                            int s1 = __shfl(idx, gb + dd + 1, 64);
                            int s2 = __shfl(idx, gb + dd + 2, 64);
                            int s3 = __shfl(idx, gb + dd + 3, 64);
                            ushort4 u0 = *(const ushort4*)(feat + (size_t)s0 * 64 + 4 * l);
                            ushort4 u1 = *(const ushort4*)(feat + (size_t)s1 * 64 + 4 * l);
                            ushort4 u2 = *(const ushort4*)(feat + (size_t)s2 * 64 + 4 * l);
                            ushort4 u3 = *(const ushort4*)(feat + (size_t)s3 * 64 + 4 * l);
                            ax += bf2f(u0.x) + bf2f(u1.x) + bf2f(u2.x) + bf2f(u3.x);
                            ay += bf2f(u0.y) + bf2f(u1.y) + bf2f(u2.y) + bf2f(u3.y);
                            az += bf2f(u0.z) + bf2f(u1.z) + bf2f(u2.z) + bf2f(u3.z);
                            aw += bf2f(u0.w) + bf2f(u1.w) + bf2f(u2.w) + bf2f(u3.w);
                        }
                        for (; dd < cnt; ++dd) {
                            int s = __shfl(idx, gb + dd, 64);
                            ushort4 u = *(const ushort4*)(feat + (size_t)s * 64 + 4 * l);
                            ax += bf2f(u.x); ay += bf2f(u.y);
                            az += bf2f(u.z); aw += bf2f(u.w);
                        }
                    }
                }
            }
            *(float4*)&amBuf[nl * SA + 4 * l] =
                make_float4(ax * inv, ay * inv, az * inv, aw * inv);
        }
    }
    __syncthreads();

    // ---- phase 2: acc = am @ Wl ----
    constexpr int CQ = CHOUT / 4;                  // 16 or 8
    constexpr int NPT = CHOUT / 16;                // 4 or 2 nodes per thread
    int cq = t % CQ, nq = t / CQ;
    float4 acc[NPT];
#pragma unroll
    for (int j = 0; j < NPT; ++j) acc[j] = make_float4(0.f, 0.f, 0.f, 0.f);

#pragma unroll 8
    for (int k = 0; k < 64; ++k) {
        float4 w = *(const float4*)&wS[k * CHOUT + 4 * cq];
#pragma unroll
        for (int j = 0; j < NPT; ++j)
            fma4(acc[j], amBuf[(nq * NPT + j) * SA + k], w);
    }
    __syncthreads();

    // ---- restage: own rows -> amBuf, Wr -> wS ----
    for (int i = t; i < 64 * 8; i += 256) {
        int nl = i >> 3, k0 = (i & 7) << 3;
        int gn = node0 + nl;
        float v[8];
        if (gn < N) {
            uint4 u = *(const uint4*)(feat + (size_t)gn * 64 + k0);
            unpack8(u, v);
        } else {
#pragma unroll
            for (int j = 0; j < 8; ++j) v[j] = 0.f;
        }
#pragma unroll
        for (int j = 0; j < 8; ++j) amBuf[nl * SA + k0 + j] = v[j];
    }
    if (isb) {
        for (int i = t; i < (64 * CHOUT) / 8; i += 256) {
            uint4 u = *(const uint4*)((const unsigned short*)Wr + (size_t)i * 8);
            float v[8]; unpack8(u, v);
#pragma unroll
            for (int j = 0; j < 8; ++j) wS[i * 8 + j] = v[j];
        }
    } else {
        for (int i = t; i < 64 * CHOUT; i += 256) wS[i] = ((const float*)Wr)[i];
    }
    __syncthreads();

    // ---- phase 3: acc += own @ Wr ----
#pragma unroll 8
    for (int k = 0; k < 64; ++k) {
        float4 w = *(const float4*)&wS[k * CHOUT + 4 * cq];
#pragma unroll
        for (int j = 0; j < NPT; ++j)
            fma4(acc[j], amBuf[(nq * NPT + j) * SA + k], w);
    }

    // ---- epilogue ----
    float4 bv = *(const float4*)&Bs[4 * cq];
#pragma unroll
    for (int j = 0; j < NPT; ++j) {
        int nl = nq * NPT + j;
        int node = node0 + nl;
        if (node >= N) continue;
        float4 r = acc[j];
        r.x += bv.x; r.y += bv.y; r.z += bv.z; r.w += bv.w;
        if (RELU) {
            r.x = fmaxf(r.x, 0.f); r.y = fmaxf(r.y, 0.f);
            r.z = fmaxf(r.z, 0.f); r.w = fmaxf(r.w, 0.f);
        }
        if (FINAL && !isb) {
            *(float4*)((float*)outp + (size_t)node * CHOUT + 4 * cq) = r;
        } else {
            ushort4 o = { f2bf(r.x), f2bf(r.y), f2bf(r.z), f2bf(r.w) };
            *(ushort4*)((unsigned short*)outp + (size_t)node * CHOUT + 4 * cq) = o;
        }
    }
}

extern "C" void kernel_launch(void* const* d_in, const int* in_sizes, int n_in,
                              void* d_out, int out_size, void* d_ws, size_t ws_size,
                              hipStream_t stream) {
    const void* x   = d_in[0];
    const int*  ei  = (const int*)d_in[1];
    const void* W1l = d_in[2];
    const void* W1r = d_in[3];
    const void* b1  = d_in[4];
    const void* W2l = d_in[5];
    const void* W2r = d_in[6];
    const void* b2  = d_in[7];

    const int N = in_sizes[0] / 64;
    const int E = in_sizes[1] / 2;
    const int NBUK = (N + (1 << BSHIFT) - 1) >> BSHIFT;   // 391 @ N=100k (<= 512)
    const int nblk = (E + CHUNK - 1) / CHUNK;             // 293 @ E=1.2M

    // ws: flags | bukTot | bukOff | rowptr[N+1] | recs[E] | esorted[E] | xb | h
    // blockHist overlays xb (dead before k_cast writes xb).
    char* base = (char*)d_ws;
    size_t off = 0;
    auto alloc = [&](size_t bytes) { size_t o = off; off = (off + bytes + 255) & ~(size_t)255; return o; };
    int* flags   = (int*)(base + alloc(256));
    int* bukTot  = (int*)(base + alloc((size_t)NBUK * 4));
    int* bukOff  = (int*)(base + alloc((size_t)(NBUK + 1) * 4));
    int* rowptr  = (int*)(base + alloc((size_t)(N + 1) * 4));
    unsigned int* recs = (unsigned int*)(base + alloc((size_t)E * 4));
    int* esorted = (int*)(base + alloc((size_t)E * 4));
    unsigned short* xb = (unsigned short*)(base + alloc((size_t)N * 64 * 2));
    unsigned short* h  = (unsigned short*)(base + alloc((size_t)N * 64 * 2));
    (void)ws_size;

    int* blockHist = (int*)xb;     // [NBUK][nblk], dead after k_part

    const int B = 256;
    int nd = 2 * E; if (nd > 2048) nd = 2048;

    k_detect<<<1, 256, 0, stream>>>(ei, nd, (const unsigned int*)x, 512, flags);
    k_bcount<<<nblk, B, 0, stream>>>(ei, flags, blockHist, E, NBUK, nblk);
    k_rowscan<<<NBUK, B, 0, stream>>>(blockHist, bukTot, nblk);
    k_toto<<<1, 512, 0, stream>>>(bukTot, bukOff, rowptr, NBUK, E, N);
    k_part<<<nblk, B, 0, stream>>>(ei, flags, blockHist, bukOff, recs, E, NBUK, nblk);
    k_cast<<<(N * 8 + B - 1) / B, B, 0, stream>>>(x, xb, N * 8, flags);
    k_csr<<<NBUK, B, 0, stream>>>(recs, bukOff, rowptr, esorted, N);

    const int ntile = (N + 63) / 64;
    // h = relu( mean_nbr(xb)@W1l + xb@W1r + b1 )
    k_fused<64, true, false><<<ntile, B, 0, stream>>>(xb, rowptr, esorted,
                                                      W1l, W1r, b1, h, N, flags);
    // out = mean_nbr(h)@W2l + h@W2r + b2
    k_fused<32, false, true><<<ntile, B, 0, stream>>>(h, rowptr, esorted,
                                                      W2l, W2r, b2, d_out, N, flags);
}